// Round 1
// baseline (16840.964 us; speedup 1.0000x reference)
//
#include <hip/hip_runtime.h>
#include <hip/hip_bf16.h>
#include <stdint.h>

using bf16 = __hip_bfloat16;
typedef __attribute__((ext_vector_type(8))) short short8;
typedef __attribute__((ext_vector_type(4))) float f32x4;

#define NB   32
#define LSQ  128
#define TDEC 63
#define HD   1024
#define ED   512
#define VOUT 32000
#define GRID_P 128

static __device__ __forceinline__ unsigned short bits_of(bf16 b) {
  return *(unsigned short*)&b;
}

// ---------------- conversion / gather kernels ----------------
__global__ void f2b4(const float* __restrict__ s, bf16* __restrict__ d, long n4) {
  long i = blockIdx.x * (long)blockDim.x + threadIdx.x;
  long st = (long)gridDim.x * blockDim.x;
  for (; i < n4; i += st) {
    float4 v = ((const float4*)s)[i];
    bf16 b0 = __float2bfloat16(v.x), b1 = __float2bfloat16(v.y);
    bf16 b2 = __float2bfloat16(v.z), b3 = __float2bfloat16(v.w);
    ushort4 o = { bits_of(b0), bits_of(b1), bits_of(b2), bits_of(b3) };
    ((ushort4*)d)[i] = o;
  }
}

__global__ void f2b_sub(const float* __restrict__ s, bf16* __restrict__ d,
                        int ld, int col0, int cols, int total) {
  for (int i = blockIdx.x * blockDim.x + threadIdx.x; i < total;
       i += gridDim.x * blockDim.x) {
    int r = i / cols, c = i - r * cols;
    d[i] = __float2bfloat16(s[(long)r * ld + col0 + c]);
  }
}

// out row r = t*32 + n ; id = ids[n*L + t]
__global__ void gather_emb(const int* __restrict__ ids, int L,
                           const float* __restrict__ table, bf16* __restrict__ out) {
  int r = blockIdx.x;
  int t = r >> 5, n = r & 31;
  long id = ids[n * L + t];
  const float* srcp = table + id * (long)ED;
  bf16* dst = out + (long)r * ED;
  for (int c = threadIdx.x; c < ED; c += blockDim.x)
    dst[c] = __float2bfloat16(srcp[c]);
}

__global__ void zero_k(float* p, int n) {
  int i = blockIdx.x * blockDim.x + threadIdx.x;
  if (i < n) p[i] = 0.f;
}

// ---------------- bf16 GEMM: C[m,n] = sum_k A[m,k]*B[n,k] + bias[n] ----------------
// A: (Mpad,K) bf16 row-major; B: (N,K) bf16 row-major; C fp32 (M,N) (or remapped rows)
// remap=1: input row gr = t*32+n  -> out row n*63+t
__global__ __launch_bounds__(256) void gemm_bt(
    const bf16* __restrict__ A, const bf16* __restrict__ B,
    float* __restrict__ C, const float* __restrict__ bias,
    int M, int N, int K, int remap)
{
  __shared__ bf16 As[128 * 64];
  __shared__ bf16 Bs[128 * 64];
  int mt = blockIdx.x, nt = blockIdx.y;
  int tid = threadIdx.x;
  int wave = tid >> 6, lane = tid & 63;
  int wr = wave & 1, wc = wave >> 1;
  f32x4 acc[4][4] = {};
  const bf16* Ab = A + (size_t)mt * 128 * K;
  const bf16* Bb = B + (size_t)nt * 128 * K;
  int lrow = tid >> 3;            // 0..31
  int lk = (tid & 7) * 8;         // 0..56
  int row16 = lane & 15, kq = (lane >> 4) * 8;

  for (int k0 = 0; k0 < K; k0 += 64) {
    __syncthreads();
#pragma unroll
    for (int it = 0; it < 4; ++it) {
      int r = it * 32 + lrow;
      __builtin_amdgcn_global_load_lds(
          (const __attribute__((address_space(1))) void*)(Ab + (size_t)r * K + k0 + lk),
          (__attribute__((address_space(3))) void*)(As + it * 2048 + tid * 8), 16, 0, 0);
      __builtin_amdgcn_global_load_lds(
          (const __attribute__((address_space(1))) void*)(Bb + (size_t)r * K + k0 + lk),
          (__attribute__((address_space(3))) void*)(Bs + it * 2048 + tid * 8), 16, 0, 0);
    }
    __syncthreads();
#pragma unroll
    for (int kk = 0; kk < 64; kk += 32) {
      short8 af[4], bfr[4];
#pragma unroll
      for (int i = 0; i < 4; ++i)
        af[i] = *(const short8*)(As + (wr * 64 + i * 16 + row16) * 64 + kk + kq);
#pragma unroll
      for (int j = 0; j < 4; ++j)
        bfr[j] = *(const short8*)(Bs + (wc * 64 + j * 16 + row16) * 64 + kk + kq);
#pragma unroll
      for (int i = 0; i < 4; ++i)
#pragma unroll
        for (int j = 0; j < 4; ++j)
          acc[i][j] = __builtin_amdgcn_mfma_f32_16x16x32_bf16(af[i], bfr[j], acc[i][j], 0, 0, 0);
    }
  }
  int quad = lane >> 4;
#pragma unroll
  for (int i = 0; i < 4; ++i) {
    int gr0 = mt * 128 + wr * 64 + i * 16;
#pragma unroll
    for (int j = 0; j < 4; ++j) {
      int gc = nt * 128 + wc * 64 + j * 16 + row16;
      float bv = bias ? bias[gc] : 0.f;
#pragma unroll
      for (int rg = 0; rg < 4; ++rg) {
        int gr = gr0 + quad * 4 + rg;
        if (gr < M) {
          long orow = remap ? ((long)(gr & 31) * TDEC + (gr >> 5)) : (long)gr;
          C[orow * N + gc] = acc[i][j][rg] + bv;
        }
      }
    }
  }
}

// ---------------- device-scope grid barrier ----------------
// Pattern: __syncthreads drains this block's stores to L2 (vmcnt 0 before
// s_barrier); thread0 does agent-release fence (L2 writeback), atomically
// arrives, spins with acquire loads; then all threads acquire-fence
// (L1/L2 invalidate) so post-barrier loads see other XCDs' writes.
// Counter is monotonic across the whole kernel (no reset race); re-zeroed
// by a zero_k graph node before each replay.
static __device__ __forceinline__ void gbar(unsigned* __restrict__ bar, unsigned want) {
  __syncthreads();
  if (threadIdx.x == 0) {
    __builtin_amdgcn_fence(__ATOMIC_RELEASE, "agent");
    __hip_atomic_fetch_add(bar, 1u, __ATOMIC_RELAXED, __HIP_MEMORY_SCOPE_AGENT);
    while (__hip_atomic_load(bar, __ATOMIC_ACQUIRE, __HIP_MEMORY_SCOPE_AGENT) < want)
      __builtin_amdgcn_s_sleep(8);
  }
  __syncthreads();
  __builtin_amdgcn_fence(__ATOMIC_ACQUIRE, "agent");
}

// ---------------- persistent encoder recurrence: all 128 steps, 1 launch ----------------
// 128 blocks x 256 thr; block b owns j in [b*8, b*8+8); one grid barrier per step.
__global__ __launch_bounds__(256, 1) void enc_rnn(
    const float* __restrict__ ig, const float* __restrict__ Whh,
    const float* __restrict__ bhh, const float* __restrict__ h0,
    float* __restrict__ hs_f, bf16* __restrict__ hs_b,
    unsigned* __restrict__ bar)
{
  __shared__ float xs[NB][260];
  int tid = threadIdx.x;
  int n = tid & 31, jl = tid >> 5;
  int j = blockIdx.x * 8 + jl;
  const float* wrow0 = Whh + (long)j * HD;
  float bj = bhh[j];
  unsigned expv = 0;
  for (int t = 0; t < LSQ; ++t) {
    const float* x = t ? hs_f + (long)(t - 1) * NB * HD : h0;
    float4 a4 = {0.f, 0.f, 0.f, 0.f};
    for (int kc = 0; kc < HD; kc += 256) {
      __syncthreads();
      // stage x[:, kc:kc+256] (32x256 fp32) via float4, coalesced
      for (int idx = tid; idx < NB * 64; idx += 256) {
        int nn = idx >> 6, c4 = idx & 63;
        *(float4*)&xs[nn][c4 * 4] = *(const float4*)(x + (long)nn * HD + kc + c4 * 4);
      }
      __syncthreads();
      const float* wrow = wrow0 + kc;
#pragma unroll 8
      for (int kk = 0; kk < 256; kk += 4) {
        float4 wv = *(const float4*)(wrow + kk);
        float4 xv = *(const float4*)(&xs[n][kk]);
        a4.x += xv.x * wv.x; a4.y += xv.y * wv.y;
        a4.z += xv.z * wv.z; a4.w += xv.w * wv.w;
      }
    }
    float acc = ig[(long)t * NB * HD + (long)n * HD + j] + bj
              + ((a4.x + a4.y) + (a4.z + a4.w));
    float hv = tanhf(acc);
    hs_f[(long)t * NB * HD + (long)n * HD + j] = hv;
    hs_b[(long)t * NB * HD + (long)n * HD + j] = __float2bfloat16(hv);
    expv += GRID_P;
    gbar(bar, expv);
  }
}

// ---------------- persistent decoder recurrence: all 63 steps, 1 launch ----------------
// 128 blocks x 256 thr, 2 grid barriers per step.
// Phase A: block b -> (an = b&31, cq = b>>5). Scores+softmax computed per-an
//   (4x redundant across cq) to avoid a third barrier; ctx computed for the
//   block's 256-column slice. Writes ctx fp32 + Zb bf16 ctx half.
// Phase B: block b -> j-slice [b*8, b*8+8); standard cell with x1=ctx (Wih[:,ED:])
//   and x2=h_prev (Whh). Writes dec_h fp32 + Zb bf16 h half.
__global__ __launch_bounds__(256, 1) void dec_rnn(
    const float* __restrict__ energy, const float* __restrict__ enc_hs,
    const int* __restrict__ src, const float* __restrict__ ig,
    const float* __restrict__ Wih, const float* __restrict__ Whh,
    const float* __restrict__ bhh, const float* __restrict__ h_init,
    float* __restrict__ ctx, float* __restrict__ dec_h,
    bf16* __restrict__ Zb, unsigned* __restrict__ bar)
{
  __shared__ float hn[HD];
  __shared__ float wl[LSQ];
  __shared__ float xs[NB][260];
  int tid = threadIdx.x;
  int b = blockIdx.x;
  int an = b & 31, cq = b >> 5;
  int n = tid & 31, jl = tid >> 5;
  int j = b * 8 + jl;
  int wave = tid >> 6, lane = tid & 63;
  const float* wih_row = Wih + (long)j * (ED + HD) + ED;
  const float* whh_row = Whh + (long)j * HD;
  float bj = bhh[j];
  unsigned expv = 0;
  for (int t = 0; t < TDEC; ++t) {
    const float* hp = t ? dec_h + (long)(t - 1) * NB * HD : h_init;

    // ---------------- phase A: scores + softmax + ctx slice ----------------
    *(float4*)&hn[tid * 4] = *(const float4*)(hp + (long)an * HD + tid * 4);
    __syncthreads();
    for (int li = 0; li < 32; ++li) {
      int l = wave * 32 + li;
      const float* er = energy + ((long)l * NB + an) * HD;
      float p = 0.f;
      for (int c = lane; c < HD; c += 64) p += er[c] * hn[c];
      for (int o = 32; o >= 1; o >>= 1) p += __shfl_xor(p, o);
      if (lane == 0) wl[l] = (src[an * LSQ + l] == 0) ? -1e9f : p;
    }
    __syncthreads();
    if (wave == 0) {
      float a = wl[lane], b2 = wl[lane + 64];
      float m = fmaxf(a, b2);
      for (int o = 32; o >= 1; o >>= 1) m = fmaxf(m, __shfl_xor(m, o));
      float ea = __expf(a - m), eb = __expf(b2 - m);
      float s = ea + eb;
      for (int o = 32; o >= 1; o >>= 1) s += __shfl_xor(s, o);
      float inv = 1.f / s;
      wl[lane] = ea * inv; wl[lane + 64] = eb * inv;
    }
    __syncthreads();
    {
      int c = cq * 256 + tid;
      float a2 = 0.f;
#pragma unroll 4
      for (int l = 0; l < LSQ; ++l)
        a2 += wl[l] * enc_hs[((long)l * NB + an) * HD + c];
      ctx[(long)an * HD + c] = a2;
      Zb[(long)t * NB * 2048 + (long)an * 2048 + HD + c] = __float2bfloat16(a2);
    }
    expv += GRID_P;
    gbar(bar, expv);

    // ---------------- phase B: cell ----------------
    float4 a4 = {0.f, 0.f, 0.f, 0.f};
    for (int pass = 0; pass < 2; ++pass) {
      const float* x = pass ? hp : ctx;
      const float* wr = pass ? whh_row : wih_row;
      for (int kc = 0; kc < HD; kc += 256) {
        __syncthreads();
        for (int idx = tid; idx < NB * 64; idx += 256) {
          int nn = idx >> 6, c4 = idx & 63;
          *(float4*)&xs[nn][c4 * 4] = *(const float4*)(x + (long)nn * HD + kc + c4 * 4);
        }
        __syncthreads();
        const float* w2 = wr + kc;
#pragma unroll 8
        for (int kk = 0; kk < 256; kk += 4) {
          float4 wv = *(const float4*)(w2 + kk);
          float4 xv = *(const float4*)(&xs[n][kk]);
          a4.x += xv.x * wv.x; a4.y += xv.y * wv.y;
          a4.z += xv.z * wv.z; a4.w += xv.w * wv.w;
        }
      }
    }
    float acc = ig[(long)t * NB * HD + (long)n * HD + j] + bj
              + ((a4.x + a4.y) + (a4.z + a4.w));
    float hv = tanhf(acc);
    dec_h[(long)t * NB * HD + (long)n * HD + j] = hv;
    Zb[(long)t * NB * 2048 + (long)n * 2048 + j] = __float2bfloat16(hv);
    expv += GRID_P;
    gbar(bar, expv);
  }
}

// ---------------- fused log-softmax: lse + subtract in one kernel ----------------
__global__ __launch_bounds__(256) void lsm_k(float* __restrict__ out) {
  int row = blockIdx.x;
  float* p = out + (long)row * VOUT;
  float m = -1e30f, s = 0.f;
  for (int c = threadIdx.x; c < VOUT; c += 256) {
    float x = p[c];
    if (x > m) { s = s * __expf(m - x) + 1.f; m = x; }
    else s += __expf(x - m);
  }
  __shared__ float sm[256], ss[256];
  sm[threadIdx.x] = m; ss[threadIdx.x] = s;
  __syncthreads();
  for (int o = 128; o > 0; o >>= 1) {
    if (threadIdx.x < o) {
      float m1 = sm[threadIdx.x], s1 = ss[threadIdx.x];
      float m2 = sm[threadIdx.x + o], s2 = ss[threadIdx.x + o];
      float M = fmaxf(m1, m2);
      ss[threadIdx.x] = s1 * __expf(m1 - M) + s2 * __expf(m2 - M);
      sm[threadIdx.x] = M;
    }
    __syncthreads();
  }
  float l = sm[0] + __logf(ss[0]);
  for (int c = threadIdx.x; c < VOUT; c += 256) p[c] -= l;
}

// ---------------- host ----------------
extern "C" void kernel_launch(void* const* d_in, const int* in_sizes, int n_in,
                              void* d_out, int out_size, void* d_ws, size_t ws_size,
                              hipStream_t stream) {
  const int*   src      = (const int*)d_in[0];
  const int*   tgt      = (const int*)d_in[1];
  const float* enc_embed= (const float*)d_in[2];
  const float* enc_Wih  = (const float*)d_in[3];
  const float* enc_bih  = (const float*)d_in[4];
  const float* enc_Whh  = (const float*)d_in[5];
  const float* enc_bhh  = (const float*)d_in[6];
  const float* dec_embed= (const float*)d_in[7];
  const float* attn_W   = (const float*)d_in[8];
  const float* attn_b   = (const float*)d_in[9];
  const float* dec_Wih  = (const float*)d_in[10];
  const float* dec_bih  = (const float*)d_in[11];
  const float* dec_Whh  = (const float*)d_in[12];
  const float* dec_bhh  = (const float*)d_in[13];
  const float* h2o_W    = (const float*)d_in[14];
  const float* h2o_b    = (const float*)d_in[15];
  float* out = (float*)d_out;

  char* ws = (char*)d_ws;
  size_t off = 0;
  auto alloc = [&](size_t bytes) { char* p = ws + off; off += (bytes + 255) & ~(size_t)255; return p; };
  bf16*  h2oW_b = (bf16*)alloc((size_t)VOUT * 2048 * 2);     // 131 MB
  bf16*  WihE_b = (bf16*)alloc((size_t)HD * ED * 2);
  bf16*  attnW_b= (bf16*)alloc((size_t)HD * HD * 2);
  bf16*  Wde_b  = (bf16*)alloc((size_t)HD * ED * 2);
  bf16*  embS_b = (bf16*)alloc((size_t)4096 * ED * 2);
  bf16*  embT_b = (bf16*)alloc((size_t)2048 * ED * 2);
  bf16*  Zb     = (bf16*)alloc((size_t)2048 * 2048 * 2);
  float* ig_enc = (float*)alloc((size_t)4096 * HD * 4);
  float* enc_hs_f=(float*)alloc((size_t)4096 * HD * 4);
  bf16*  enc_hs_b=(bf16*)alloc((size_t)4096 * HD * 2);
  float* ig_dec = (float*)alloc((size_t)2048 * HD * 4);
  float* dec_h  = (float*)alloc((size_t)2016 * HD * 4);
  float* ctx    = (float*)alloc((size_t)NB * HD * 4);
  float* h0     = (float*)alloc((size_t)NB * HD * 4);
  unsigned* bars= (unsigned*)alloc(512);                      // bars[0]=enc, bars[64]=dec
  // energy aliases ig_enc: ig_enc is dead after the encoder recurrence,
  // energy is produced strictly after it (stream order). Saves 16 MB peak ws.
  float* energy = ig_enc;
  (void)ws_size; (void)in_sizes; (void)n_in; (void)out_size;

  // weight conversions + embedding gathers
  f2b4<<<4096, 256, 0, stream>>>(h2o_W, h2oW_b, (long)VOUT * 2048 / 4);
  f2b4<<<512, 256, 0, stream>>>(enc_Wih, WihE_b, (long)HD * ED / 4);
  f2b4<<<1024, 256, 0, stream>>>(attn_W, attnW_b, (long)HD * HD / 4);
  f2b_sub<<<1024, 256, 0, stream>>>(dec_Wih, Wde_b, ED + HD, 0, ED, HD * ED);
  gather_emb<<<4096, 128, 0, stream>>>(src, LSQ, enc_embed, embS_b);
  gather_emb<<<2016, 128, 0, stream>>>(tgt, 64, dec_embed, embT_b);
  zero_k<<<128, 256, 0, stream>>>(h0, NB * HD);
  zero_k<<<1, 128, 0, stream>>>((float*)bars, 128);   // re-zero barrier counters every replay

  // encoder input gates: (4096,512)x(1024,512)^T
  gemm_bt<<<dim3(32, 8), 256, 0, stream>>>(embS_b, WihE_b, ig_enc, enc_bih, 4096, HD, ED, 0);

  // encoder recurrence: ONE persistent kernel, 128 grid barriers
  enc_rnn<<<GRID_P, 256, 0, stream>>>(ig_enc, enc_Whh, enc_bhh, h0,
                                      enc_hs_f, enc_hs_b, bars);

  // decoder input gates from embeddings: (2016,512)x(1024,512)^T
  gemm_bt<<<dim3(16, 8), 256, 0, stream>>>(embT_b, Wde_b, ig_dec, dec_bih, 2016, HD, ED, 0);

  // energy = enc_hs @ attn_W.T + attn_b   (overwrites ig_enc — now dead)
  gemm_bt<<<dim3(32, 8), 256, 0, stream>>>(enc_hs_b, attnW_b, energy, attn_b, 4096, HD, HD, 0);

  // decoder recurrence: ONE persistent kernel, 126 grid barriers
  dec_rnn<<<GRID_P, 256, 0, stream>>>(energy, enc_hs_f, src, ig_dec,
                                      dec_Wih, dec_Whh, dec_bhh,
                                      enc_hs_f + (long)(LSQ - 1) * NB * HD,
                                      ctx, dec_h, Zb, bars + 64);

  // big output projection: (2016,2048) x (32000,2048)^T -> out rows n*63+t
  gemm_bt<<<dim3(16, 250), 256, 0, stream>>>(Zb, h2oW_b, out, h2o_b, 2016, VOUT, 2048, 1);

  // fused log-softmax over vocab
  lsm_k<<<2016, 256, 0, stream>>>(out);
}

// Round 2
// 6507.204 us; speedup vs baseline: 2.5880x; 2.5880x over previous
//
#include <hip/hip_runtime.h>
#include <hip/hip_bf16.h>
#include <stdint.h>

using bf16 = __hip_bfloat16;
typedef __attribute__((ext_vector_type(8))) short short8;
typedef __attribute__((ext_vector_type(4))) float f32x4;

#define NB   32
#define LSQ  128
#define TDEC 63
#define HD   1024
#define ED   512
#define VOUT 32000
#define GRID_R 16          // blocks in each persistent recurrence kernel

static __device__ __forceinline__ unsigned short bits_of(bf16 b) {
  return *(unsigned short*)&b;
}
static __device__ __forceinline__ float b2f(short u) {
  union { float f; unsigned i; } x; x.i = ((unsigned)(unsigned short)u) << 16; return x.f;
}
static __device__ __forceinline__ short8 cvt8(float4 a, float4 b) {
  short8 r;
  r[0] = bits_of(__float2bfloat16(a.x)); r[1] = bits_of(__float2bfloat16(a.y));
  r[2] = bits_of(__float2bfloat16(a.z)); r[3] = bits_of(__float2bfloat16(a.w));
  r[4] = bits_of(__float2bfloat16(b.x)); r[5] = bits_of(__float2bfloat16(b.y));
  r[6] = bits_of(__float2bfloat16(b.z)); r[7] = bits_of(__float2bfloat16(b.w));
  return r;
}

// ---------------- conversion / gather kernels ----------------
__global__ void f2b4(const float* __restrict__ s, bf16* __restrict__ d, long n4) {
  long i = blockIdx.x * (long)blockDim.x + threadIdx.x;
  long st = (long)gridDim.x * blockDim.x;
  for (; i < n4; i += st) {
    float4 v = ((const float4*)s)[i];
    bf16 b0 = __float2bfloat16(v.x), b1 = __float2bfloat16(v.y);
    bf16 b2 = __float2bfloat16(v.z), b3 = __float2bfloat16(v.w);
    ushort4 o = { bits_of(b0), bits_of(b1), bits_of(b2), bits_of(b3) };
    ((ushort4*)d)[i] = o;
  }
}

__global__ void f2b_sub(const float* __restrict__ s, bf16* __restrict__ d,
                        int ld, int col0, int cols, int total) {
  for (int i = blockIdx.x * blockDim.x + threadIdx.x; i < total;
       i += gridDim.x * blockDim.x) {
    int r = i / cols, c = i - r * cols;
    d[i] = __float2bfloat16(s[(long)r * ld + col0 + c]);
  }
}

// out row r = t*32 + n ; id = ids[n*L + t]
__global__ void gather_emb(const int* __restrict__ ids, int L,
                           const float* __restrict__ table, bf16* __restrict__ out) {
  int r = blockIdx.x;
  int t = r >> 5, n = r & 31;
  long id = ids[n * L + t];
  const float* srcp = table + id * (long)ED;
  bf16* dst = out + (long)r * ED;
  for (int c = threadIdx.x; c < ED; c += blockDim.x)
    dst[c] = __float2bfloat16(srcp[c]);
}

__global__ void zero_k(float* p, int n) {
  int i = blockIdx.x * blockDim.x + threadIdx.x;
  if (i < n) p[i] = 0.f;
}

// ---------------- bf16 GEMM: C[m,n] = sum_k A[m,k]*B[n,k] + bias[n] ----------------
__global__ __launch_bounds__(256) void gemm_bt(
    const bf16* __restrict__ A, const bf16* __restrict__ B,
    float* __restrict__ C, const float* __restrict__ bias,
    int M, int N, int K, int remap)
{
  __shared__ bf16 As[128 * 64];
  __shared__ bf16 Bs[128 * 64];
  int mt = blockIdx.x, nt = blockIdx.y;
  int tid = threadIdx.x;
  int wave = tid >> 6, lane = tid & 63;
  int wr = wave & 1, wc = wave >> 1;
  f32x4 acc[4][4] = {};
  const bf16* Ab = A + (size_t)mt * 128 * K;
  const bf16* Bb = B + (size_t)nt * 128 * K;
  int lrow = tid >> 3;
  int lk = (tid & 7) * 8;
  int row16 = lane & 15, kq = (lane >> 4) * 8;

  for (int k0 = 0; k0 < K; k0 += 64) {
    __syncthreads();
#pragma unroll
    for (int it = 0; it < 4; ++it) {
      int r = it * 32 + lrow;
      __builtin_amdgcn_global_load_lds(
          (const __attribute__((address_space(1))) void*)(Ab + (size_t)r * K + k0 + lk),
          (__attribute__((address_space(3))) void*)(As + it * 2048 + tid * 8), 16, 0, 0);
      __builtin_amdgcn_global_load_lds(
          (const __attribute__((address_space(1))) void*)(Bb + (size_t)r * K + k0 + lk),
          (__attribute__((address_space(3))) void*)(Bs + it * 2048 + tid * 8), 16, 0, 0);
    }
    __syncthreads();
#pragma unroll
    for (int kk = 0; kk < 64; kk += 32) {
      short8 af[4], bfr[4];
#pragma unroll
      for (int i = 0; i < 4; ++i)
        af[i] = *(const short8*)(As + (wr * 64 + i * 16 + row16) * 64 + kk + kq);
#pragma unroll
      for (int j = 0; j < 4; ++j)
        bfr[j] = *(const short8*)(Bs + (wc * 64 + j * 16 + row16) * 64 + kk + kq);
#pragma unroll
      for (int i = 0; i < 4; ++i)
#pragma unroll
        for (int j = 0; j < 4; ++j)
          acc[i][j] = __builtin_amdgcn_mfma_f32_16x16x32_bf16(af[i], bfr[j], acc[i][j], 0, 0, 0);
    }
  }
  int quad = lane >> 4;
#pragma unroll
  for (int i = 0; i < 4; ++i) {
    int gr0 = mt * 128 + wr * 64 + i * 16;
#pragma unroll
    for (int j = 0; j < 4; ++j) {
      int gc = nt * 128 + wc * 64 + j * 16 + row16;
      float bv = bias ? bias[gc] : 0.f;
#pragma unroll
      for (int rg = 0; rg < 4; ++rg) {
        int gr = gr0 + quad * 4 + rg;
        if (gr < M) {
          long orow = remap ? ((long)(gr & 31) * TDEC + (gr >> 5)) : (long)gr;
          C[orow * N + gc] = acc[i][j][rg] + bv;
        }
      }
    }
  }
}

// ---------------- device-scope grid barrier (RELAXED spin — no inv storm) ----------------
static __device__ __forceinline__ void gbar(unsigned* __restrict__ bar, unsigned want) {
  __syncthreads();
  if (threadIdx.x == 0) {
    __builtin_amdgcn_fence(__ATOMIC_RELEASE, "agent");
    __hip_atomic_fetch_add(bar, 1u, __ATOMIC_RELAXED, __HIP_MEMORY_SCOPE_AGENT);
    while (__hip_atomic_load(bar, __ATOMIC_RELAXED, __HIP_MEMORY_SCOPE_AGENT) < want)
      __builtin_amdgcn_s_sleep(1);
  }
  __syncthreads();
  __builtin_amdgcn_fence(__ATOMIC_ACQUIRE, "agent");
}

// ---------------- persistent encoder: weights in REGISTERS, h in LDS, MFMA cell ----
// 16 blocks x 256 thr. Block b owns output cols [b*64, b*64+64); wave w owns 16 cols.
// Per lane: 32 B-frags (128 VGPR) of Whh held for the whole kernel.
__global__ __launch_bounds__(256, 1) void enc_rnn(
    const float* __restrict__ ig, const float* __restrict__ Whh,
    const float* __restrict__ bhh,
    bf16* __restrict__ hb0, bf16* __restrict__ hb1,
    bf16* __restrict__ hs_b, unsigned* __restrict__ bar)
{
  __shared__ bf16 hl[32 * 1032];           // padded rows: 2-way banks only
  int tid = threadIdx.x, b = blockIdx.x;
  int wave = tid >> 6, lane = tid & 63;
  int row16 = lane & 15, kq8 = (lane >> 4) * 8;
  int j0 = b * 64 + wave * 16;
  int j = j0 + row16;
  float bj = bhh[j];

  short8 bw[32];
#pragma unroll
  for (int kt = 0; kt < 32; ++kt) {
    const float* wp = Whh + (size_t)j * HD + kt * 32 + kq8;
    bw[kt] = cvt8(*(const float4*)wp, *(const float4*)(wp + 4));
  }

  unsigned expv = 0;
  for (int t = 0; t < LSQ; ++t) {
    const bf16* hp = (t & 1) ? hb1 : hb0;
    bf16* hn = (t & 1) ? hb0 : hb1;
    // stage h (32x1024 bf16) into padded LDS
#pragma unroll
    for (int c = 0; c < 16; ++c) {
      int flat = c * 256 + tid;
      int r = flat >> 7, c8 = (flat & 127) * 8;
      *(short8*)(hl + r * 1032 + c8) = *(const short8*)(hp + r * 1024 + c8);
    }
    __syncthreads();
    f32x4 acc0 = {0.f, 0.f, 0.f, 0.f}, acc1 = {0.f, 0.f, 0.f, 0.f};
#pragma unroll
    for (int kt = 0; kt < 32; ++kt) {
      short8 a0 = *(const short8*)(hl + row16 * 1032 + kt * 32 + kq8);
      short8 a1 = *(const short8*)(hl + (16 + row16) * 1032 + kt * 32 + kq8);
      acc0 = __builtin_amdgcn_mfma_f32_16x16x32_bf16(a0, bw[kt], acc0, 0, 0, 0);
      acc1 = __builtin_amdgcn_mfma_f32_16x16x32_bf16(a1, bw[kt], acc1, 0, 0, 0);
    }
    int nb = (lane >> 4) * 4;
#pragma unroll
    for (int mt = 0; mt < 2; ++mt) {
      f32x4 a = mt ? acc1 : acc0;
#pragma unroll
      for (int rg = 0; rg < 4; ++rg) {
        int n = mt * 16 + nb + rg;
        float v = tanhf(a[rg] + ig[((size_t)t * 32 + n) * HD + j] + bj);
        bf16 hv = __float2bfloat16(v);
        hn[n * HD + j] = hv;
        hs_b[((size_t)t * 32 + n) * HD + j] = hv;
      }
    }
    expv += GRID_R;
    gbar(bar, expv);
  }
}

// ---------------- persistent decoder: attention GEMVs + MFMA cell ----------------
// 16 blocks x 256 thr, 2 barriers/step.
// Phase A: block b owns batch rows n0=2b, 2b+1 -> scores (256 parallel 1024-dots),
//   softmax (2-wave reduce), ctx (coalesced bf16), written to Zb[t] ctx half.
// Phase B: block b owns cols [b*64,+64); 64 B-frags/lane (256 VGPR): kt<32 = Wih_ctx,
//   kt>=32 = Whh. A-frags from ctx_lds / h_lds.
__global__ __launch_bounds__(256, 1) void dec_rnn(
    const float* __restrict__ energy, const bf16* __restrict__ ehs_b,
    const int* __restrict__ src, const float* __restrict__ ig,
    const float* __restrict__ Wih, const float* __restrict__ Whh,
    const float* __restrict__ bhh, const bf16* __restrict__ hinit,
    bf16* __restrict__ hd0, bf16* __restrict__ hd1,
    bf16* __restrict__ Zb, unsigned* __restrict__ bar)
{
  __shared__ bf16 hl[32 * 1032];      // 66 KB  h
  __shared__ bf16 cl[32 * 1032];      // 66 KB  ctx
  __shared__ float hn32[2][1024];     // 8 KB   fp32 h rows for this block's n-pair
  __shared__ float wl[2][128];        // softmax weights
  __shared__ float red[2][4];         // cross-wave reduce
  int tid = threadIdx.x, b = blockIdx.x;
  int wave = tid >> 6, lane = tid & 63;
  int row16 = lane & 15, kq8 = (lane >> 4) * 8;
  int j0 = b * 64 + wave * 16;
  int j = j0 + row16;
  float bj = bhh[j];
  int n0 = b * 2;
  int n01 = tid >> 7, lA = tid & 127;
  int nA = n0 + n01;
  bool maskA = (src[nA * LSQ + lA] == 0);
  const float* erow = energy + ((size_t)lA * 32 + nA) * HD;

  short8 bw[64];
#pragma unroll
  for (int kt = 0; kt < 32; ++kt) {
    const float* wp = Wih + (size_t)j * (ED + HD) + ED + kt * 32 + kq8;
    bw[kt] = cvt8(*(const float4*)wp, *(const float4*)(wp + 4));
  }
#pragma unroll
  for (int kt = 0; kt < 32; ++kt) {
    const float* wp = Whh + (size_t)j * HD + kt * 32 + kq8;
    bw[32 + kt] = cvt8(*(const float4*)wp, *(const float4*)(wp + 4));
  }

  unsigned expv = 0;
  for (int t = 0; t < TDEC; ++t) {
    const bf16* hp = (t == 0) ? hinit : ((t & 1) ? hd1 : hd0);
    bf16* hnout = (t & 1) ? hd0 : hd1;
    bf16* zrow = Zb + (size_t)t * 32 * 2048;

    // ---- stage h into LDS ----
#pragma unroll
    for (int c = 0; c < 16; ++c) {
      int flat = c * 256 + tid;
      int r = flat >> 7, c8 = (flat & 127) * 8;
      *(short8*)(hl + r * 1032 + c8) = *(const short8*)(hp + r * 1024 + c8);
    }
    __syncthreads();
    // ---- fp32 copies of this block's two h rows ----
#pragma unroll
    for (int c = 0; c < 8; ++c) {
      int flat = c * 256 + tid;
      int rr = flat >> 10, cc = flat & 1023;
      hn32[rr][cc] = b2f(*(const short*)(hl + (n0 + rr) * 1032 + cc));
    }
    __syncthreads();

    // ---- scores: 256 parallel 1024-dots ----
    float sc = 0.f;
#pragma unroll 8
    for (int c = 0; c < 1024; c += 4) {
      float4 ev = *(const float4*)(erow + c);
      float4 hv = *(const float4*)(&hn32[n01][c]);
      sc += ev.x * hv.x + ev.y * hv.y + ev.z * hv.z + ev.w * hv.w;
    }
    if (maskA) sc = -1e9f;
    // ---- softmax over 128 threads (2 waves) per n ----
    float m = sc;
#pragma unroll
    for (int o = 32; o >= 1; o >>= 1) m = fmaxf(m, __shfl_xor(m, o));
    if (lane == 0) red[0][wave] = m;
    __syncthreads();
    m = fmaxf(red[0][n01 * 2], red[0][n01 * 2 + 1]);
    float e = __expf(sc - m);
    float s = e;
#pragma unroll
    for (int o = 32; o >= 1; o >>= 1) s += __shfl_xor(s, o);
    if (lane == 0) red[1][wave] = s;
    __syncthreads();
    s = red[1][n01 * 2] + red[1][n01 * 2 + 1];
    wl[n01][lA] = e / s;
    __syncthreads();

    // ---- ctx: coalesced bf16 reads, write Zb[t] ctx half ----
    {
      int c0 = lA * 8;
      float ca[8] = {0.f, 0.f, 0.f, 0.f, 0.f, 0.f, 0.f, 0.f};
#pragma unroll 4
      for (int l = 0; l < 128; ++l) {
        float wv = wl[n01][l];
        short8 eh = *(const short8*)(ehs_b + ((size_t)l * 32 + nA) * HD + c0);
#pragma unroll
        for (int q = 0; q < 8; ++q) ca[q] += wv * b2f(eh[q]);
      }
      short8 co;
#pragma unroll
      for (int q = 0; q < 8; ++q) co[q] = bits_of(__float2bfloat16(ca[q]));
      *(short8*)(zrow + (size_t)nA * 2048 + 1024 + c0) = co;
    }
    expv += GRID_R;
    gbar(bar, expv);

    // ---- stage full ctx from Zb[t] into LDS ----
#pragma unroll
    for (int c = 0; c < 16; ++c) {
      int flat = c * 256 + tid;
      int r = flat >> 7, c8 = (flat & 127) * 8;
      *(short8*)(cl + r * 1032 + c8) = *(const short8*)(zrow + (size_t)r * 2048 + 1024 + c8);
    }
    __syncthreads();

    // ---- MFMA cell: K = 1024(ctx) + 1024(h) ----
    f32x4 acc0 = {0.f, 0.f, 0.f, 0.f}, acc1 = {0.f, 0.f, 0.f, 0.f};
#pragma unroll
    for (int kt = 0; kt < 32; ++kt) {
      short8 a0 = *(const short8*)(cl + row16 * 1032 + kt * 32 + kq8);
      short8 a1 = *(const short8*)(cl + (16 + row16) * 1032 + kt * 32 + kq8);
      acc0 = __builtin_amdgcn_mfma_f32_16x16x32_bf16(a0, bw[kt], acc0, 0, 0, 0);
      acc1 = __builtin_amdgcn_mfma_f32_16x16x32_bf16(a1, bw[kt], acc1, 0, 0, 0);
    }
#pragma unroll
    for (int kt = 0; kt < 32; ++kt) {
      short8 a0 = *(const short8*)(hl + row16 * 1032 + kt * 32 + kq8);
      short8 a1 = *(const short8*)(hl + (16 + row16) * 1032 + kt * 32 + kq8);
      acc0 = __builtin_amdgcn_mfma_f32_16x16x32_bf16(a0, bw[32 + kt], acc0, 0, 0, 0);
      acc1 = __builtin_amdgcn_mfma_f32_16x16x32_bf16(a1, bw[32 + kt], acc1, 0, 0, 0);
    }
    int nb = (lane >> 4) * 4;
#pragma unroll
    for (int mt = 0; mt < 2; ++mt) {
      f32x4 a = mt ? acc1 : acc0;
#pragma unroll
      for (int rg = 0; rg < 4; ++rg) {
        int n = mt * 16 + nb + rg;
        float v = tanhf(a[rg] + ig[((size_t)t * 32 + n) * HD + j] + bj);
        bf16 hv = __float2bfloat16(v);
        hnout[n * HD + j] = hv;
        zrow[(size_t)n * 2048 + j] = hv;
      }
    }
    expv += GRID_R;
    gbar(bar, expv);
  }
}

// ---------------- fused log-softmax ----------------
__global__ __launch_bounds__(256) void lsm_k(float* __restrict__ out) {
  int row = blockIdx.x;
  float* p = out + (long)row * VOUT;
  float m = -1e30f, s = 0.f;
  for (int c = threadIdx.x; c < VOUT; c += 256) {
    float x = p[c];
    if (x > m) { s = s * __expf(m - x) + 1.f; m = x; }
    else s += __expf(x - m);
  }
  __shared__ float sm[256], ss[256];
  sm[threadIdx.x] = m; ss[threadIdx.x] = s;
  __syncthreads();
  for (int o = 128; o > 0; o >>= 1) {
    if (threadIdx.x < o) {
      float m1 = sm[threadIdx.x], s1 = ss[threadIdx.x];
      float m2 = sm[threadIdx.x + o], s2 = ss[threadIdx.x + o];
      float M = fmaxf(m1, m2);
      ss[threadIdx.x] = s1 * __expf(m1 - M) + s2 * __expf(m2 - M);
      sm[threadIdx.x] = M;
    }
    __syncthreads();
  }
  float l = sm[0] + __logf(ss[0]);
  for (int c = threadIdx.x; c < VOUT; c += 256) p[c] -= l;
}

// ---------------- host ----------------
extern "C" void kernel_launch(void* const* d_in, const int* in_sizes, int n_in,
                              void* d_out, int out_size, void* d_ws, size_t ws_size,
                              hipStream_t stream) {
  const int*   src      = (const int*)d_in[0];
  const int*   tgt      = (const int*)d_in[1];
  const float* enc_embed= (const float*)d_in[2];
  const float* enc_Wih  = (const float*)d_in[3];
  const float* enc_bih  = (const float*)d_in[4];
  const float* enc_Whh  = (const float*)d_in[5];
  const float* enc_bhh  = (const float*)d_in[6];
  const float* dec_embed= (const float*)d_in[7];
  const float* attn_W   = (const float*)d_in[8];
  const float* attn_b   = (const float*)d_in[9];
  const float* dec_Wih  = (const float*)d_in[10];
  const float* dec_bih  = (const float*)d_in[11];
  const float* dec_Whh  = (const float*)d_in[12];
  const float* dec_bhh  = (const float*)d_in[13];
  const float* h2o_W    = (const float*)d_in[14];
  const float* h2o_b    = (const float*)d_in[15];
  float* out = (float*)d_out;

  char* ws = (char*)d_ws;
  size_t off = 0;
  auto alloc = [&](size_t bytes) { char* p = ws + off; off += (bytes + 255) & ~(size_t)255; return p; };
  bf16*  h2oW_b = (bf16*)alloc((size_t)VOUT * 2048 * 2);     // 131 MB
  bf16*  WihE_b = (bf16*)alloc((size_t)HD * ED * 2);
  bf16*  attnW_b= (bf16*)alloc((size_t)HD * HD * 2);
  bf16*  Wde_b  = (bf16*)alloc((size_t)HD * ED * 2);
  bf16*  embS_b = (bf16*)alloc((size_t)4096 * ED * 2);
  bf16*  embT_b = (bf16*)alloc((size_t)2048 * ED * 2);
  bf16*  Zb     = (bf16*)alloc((size_t)2048 * 2048 * 2);
  float* ig_enc = (float*)alloc((size_t)4096 * HD * 4);
  bf16*  enc_hs_b=(bf16*)alloc((size_t)4096 * HD * 2);
  float* ig_dec = (float*)alloc((size_t)2048 * HD * 4);
  bf16*  hbe0   = (bf16*)alloc((size_t)NB * HD * 2);
  bf16*  hbe1   = (bf16*)alloc((size_t)NB * HD * 2);
  bf16*  hdd0   = (bf16*)alloc((size_t)NB * HD * 2);
  bf16*  hdd1   = (bf16*)alloc((size_t)NB * HD * 2);
  unsigned* bars= (unsigned*)alloc(512);                     // bars[0]=enc, bars[64]=dec
  float* energy = ig_enc;   // ig_enc dead after enc_rnn; energy written after
  (void)ws_size; (void)in_sizes; (void)n_in; (void)out_size;

  // weight conversions + embedding gathers
  f2b4<<<4096, 256, 0, stream>>>(h2o_W, h2oW_b, (long)VOUT * 2048 / 4);
  f2b4<<<512, 256, 0, stream>>>(enc_Wih, WihE_b, (long)HD * ED / 4);
  f2b4<<<1024, 256, 0, stream>>>(attn_W, attnW_b, (long)HD * HD / 4);
  f2b_sub<<<1024, 256, 0, stream>>>(dec_Wih, Wde_b, ED + HD, 0, ED, HD * ED);
  gather_emb<<<4096, 128, 0, stream>>>(src, LSQ, enc_embed, embS_b);
  gather_emb<<<2016, 128, 0, stream>>>(tgt, 64, dec_embed, embT_b);
  zero_k<<<64, 256, 0, stream>>>((float*)hbe0, NB * HD / 2);   // bf16 zeros
  zero_k<<<1, 128, 0, stream>>>((float*)bars, 128);            // barrier counters

  // encoder input gates: (4096,512)x(1024,512)^T
  gemm_bt<<<dim3(32, 8), 256, 0, stream>>>(embS_b, WihE_b, ig_enc, enc_bih, 4096, HD, ED, 0);

  // encoder recurrence: 16 blocks, weights in registers, 1 barrier/step
  enc_rnn<<<GRID_R, 256, 0, stream>>>(ig_enc, enc_Whh, enc_bhh,
                                      hbe0, hbe1, enc_hs_b, bars);

  // decoder input gates from embeddings: (2016,512)x(1024,512)^T
  gemm_bt<<<dim3(16, 8), 256, 0, stream>>>(embT_b, Wde_b, ig_dec, dec_bih, 2016, HD, ED, 0);

  // energy = enc_hs @ attn_W.T + attn_b   (overwrites ig_enc — now dead)
  gemm_bt<<<dim3(32, 8), 256, 0, stream>>>(enc_hs_b, attnW_b, energy, attn_b, 4096, HD, HD, 0);

  // decoder recurrence: 16 blocks, 2 barriers/step; h_init = encoder final h (hbe0)
  dec_rnn<<<GRID_R, 256, 0, stream>>>(energy, enc_hs_b, src, ig_dec,
                                      dec_Wih, dec_Whh, dec_bhh,
                                      hbe0, hdd0, hdd1, Zb, bars + 64);

  // big output projection: (2016,2048) x (32000,2048)^T -> out rows n*63+t
  gemm_bt<<<dim3(16, 250), 256, 0, stream>>>(Zb, h2oW_b, out, h2o_b, 2016, VOUT, 2048, 1);

  // fused log-softmax over vocab
  lsm_k<<<2016, 256, 0, stream>>>(out);
}